// Round 11
// baseline (312.458 us; speedup 1.0000x reference)
//
#include <hip/hip_runtime.h>

// Problem constants (match reference setup_inputs)
constexpr int B = 64, T = 256, M = 16, A = 32, H = 64;
constexpr int ROWB = 11264;   // G row stride bytes: 10368 used (81g x 64gc x bf16) + pad = 11 x 1KB

typedef __attribute__((ext_vector_type(8))) short bf16x8;
typedef __attribute__((ext_vector_type(4))) float f32x4;

// ws layout
constexpr size_t OW = 0;                               // Wb  bf16 [5184][32]
constexpr size_t OX = 332800;                          // xb  bf16 [B*T][32]
constexpr size_t OB = OX + (size_t)B * T * A * 2;      // bias f32 [5184]
constexpr size_t OG = OB + 21504;                      // G rows (row-major bf16)

__device__ __forceinline__ float blo(unsigned u) { return __builtin_bit_cast(float, u << 16); }
__device__ __forceinline__ float bhi(unsigned u) { return __builtin_bit_cast(float, u & 0xffff0000u); }

// ---------------------------------------------------------------------------
// Prep: convert W (Wj|Wr|Wo) and x_a to bf16 (RNE); concat biases to f32.
// ---------------------------------------------------------------------------
__global__ __launch_bounds__(256) void prep_kernel(
    const float* __restrict__ x_a,
    const float* __restrict__ Wj, const float* __restrict__ Wr,
    const float* __restrict__ Wo,
    const float* __restrict__ bj, const float* __restrict__ br,
    const float* __restrict__ bo, unsigned char* ws)
{
    const int nW = 5184 * 32, nX = B * T * A, nB = 5184;
    int idx = blockIdx.x * 256 + threadIdx.x;
    if (idx >= nW + nX + nB) return;
    if (idx < nW + nX) {
        float v;
        ushort* dst;
        if (idx < nW) {
            int row = idx >> 5;
            v = (row < 1024) ? Wj[idx] : (row < 5120) ? Wr[idx - 1024 * 32] : Wo[idx - 5120 * 32];
            dst = (ushort*)(ws + OW) + idx;
        } else {
            v = x_a[idx - nW];
            dst = (ushort*)(ws + OX) + (idx - nW);
        }
        unsigned u = __builtin_bit_cast(unsigned, v);
        *dst = (ushort)((u + 0x7fffu + ((u >> 16) & 1u)) >> 16);   // RNE
    } else {
        int row = idx - nW - nX;
        float v = (row < 1024) ? bj[row] : (row < 5120) ? br[row - 1024] : bo[row - 5120];
        ((float*)(ws + OB))[row] = v;
    }
}

// ---------------------------------------------------------------------------
// Gate kernel (MFMA + LDS transpose): block = 32 rows x all 81 groups.
// Swapped GEMM: D[gc][t] = mfma(A = W-slab, B = x-tile); lane holds
// (t = lane&15, gc = 4*(lane>>4)+reg). Per group-PAIR, the wave stages its
// 2x(16t x 128gc) bf16 tiles in LDS and stores row-major G with 256B
// contiguous cache-line-aligned runs. Group 80 is duplicated into row pad.
// ---------------------------------------------------------------------------
__global__ __launch_bounds__(256) void gate_kernel(
    unsigned char* ws, int t0, int chunk)
{
    const int tid = threadIdx.x, lane = tid & 63, wv = tid >> 6;
    const int l15 = lane & 15, l4 = lane >> 4;
    const ushort* Wb = (const ushort*)(ws + OW);
    const ushort* xb = (const ushort*)(ws + OX);
    const float*  bc = (const float*)(ws + OB);
    unsigned char* G = ws + OG;

    __shared__ ushort tr[4][32][152];   // per-wave [2 tiles x 16 t][2 groups x 64 gc + pad]

    const int r0 = blockIdx.x * 32;     // 32 consecutive rows, same batch (chunk % 32 == 0)
    const int bb = r0 / chunk, tcc = r0 % chunk;
    const long xrow0 = (long)bb * T + t0 + tcc;

    const bf16x8 bx0 = *(const bf16x8*)(xb + (xrow0 + l15) * 32 + l4 * 8);
    const bf16x8 bx1 = *(const bf16x8*)(xb + (xrow0 + 16 + l15) * 32 + l4 * 8);

    const int p0 = wv * 10;
    const int pend = p0 + ((wv == 3) ? 11 : 10);   // wave3: pairs 30..39 + (80,dup)
    const int rr = lane >> 4, c16 = lane & 15;
    const f32x4 zero = {0.f, 0.f, 0.f, 0.f};

    for (int p = p0; p < pend; ++p) {
        #pragma unroll
        for (int gl = 0; gl < 2; ++gl) {
            int g = 2 * p + gl;
            if (g > 80) g = 80;        // duplicate o-gate into the pad slot
            f32x4 d0[4], d1[4];
            #pragma unroll
            for (int ct = 0; ct < 4; ++ct) {
                const bf16x8 aW =
                    *(const bf16x8*)(Wb + (size_t)(g * 64 + ct * 16 + l15) * 32 + l4 * 8);
                d0[ct] = __builtin_amdgcn_mfma_f32_16x16x32_bf16(aW, bx0, zero, 0, 0, 0);
                d1[ct] = __builtin_amdgcn_mfma_f32_16x16x32_bf16(aW, bx1, zero, 0, 0, 0);
                const float4 bv = *(const float4*)(bc + g * 64 + ct * 16 + l4 * 4);
                d0[ct][0] += bv.x; d0[ct][1] += bv.y; d0[ct][2] += bv.z; d0[ct][3] += bv.w;
                d1[ct][0] += bv.x; d1[ct][1] += bv.y; d1[ct][2] += bv.z; d1[ct][3] += bv.w;
            }

            if (g < 80) {   // softmax over 64 gate-cols: lane-local 16 + shfl(16,32)
                float s0 = 0.f, s1 = 0.f;
                #pragma unroll
                for (int ct = 0; ct < 4; ++ct)
                    #pragma unroll
                    for (int j = 0; j < 4; ++j) {
                        d0[ct][j] = __expf(d0[ct][j]); s0 += d0[ct][j];
                        d1[ct][j] = __expf(d1[ct][j]); s1 += d1[ct][j];
                    }
                s0 += __shfl_xor(s0, 16); s0 += __shfl_xor(s0, 32);
                s1 += __shfl_xor(s1, 16); s1 += __shfl_xor(s1, 32);
                const float i0 = __fdividef(1.f, s0), i1 = __fdividef(1.f, s1);
                #pragma unroll
                for (int ct = 0; ct < 4; ++ct)
                    #pragma unroll
                    for (int j = 0; j < 4; ++j) { d0[ct][j] *= i0; d1[ct][j] *= i1; }
            } else {        // out-gate sigmoid
                #pragma unroll
                for (int ct = 0; ct < 4; ++ct)
                    #pragma unroll
                    for (int j = 0; j < 4; ++j) {
                        d0[ct][j] = __fdividef(1.f, 1.f + __expf(-d0[ct][j]));
                        d1[ct][j] = __fdividef(1.f, 1.f + __expf(-d1[ct][j]));
                    }
            }

            #pragma unroll
            for (int ct = 0; ct < 4; ++ct) {   // pack bf16, write LDS tiles
                unsigned lo0, hi0, lo1, hi1;
                asm volatile("v_cvt_pk_bf16_f32 %0, %1, %2" : "=v"(lo0) : "v"(d0[ct][0]), "v"(d0[ct][1]));
                asm volatile("v_cvt_pk_bf16_f32 %0, %1, %2" : "=v"(hi0) : "v"(d0[ct][2]), "v"(d0[ct][3]));
                asm volatile("v_cvt_pk_bf16_f32 %0, %1, %2" : "=v"(lo1) : "v"(d1[ct][0]), "v"(d1[ct][1]));
                asm volatile("v_cvt_pk_bf16_f32 %0, %1, %2" : "=v"(hi1) : "v"(d1[ct][2]), "v"(d1[ct][3]));
                *(uint2*)&tr[wv][l15][gl * 64 + ct * 16 + l4 * 4]      = make_uint2(lo0, hi0);
                *(uint2*)&tr[wv][16 + l15][gl * 64 + ct * 16 + l4 * 4] = make_uint2(lo1, hi1);
            }
        }

        // same-wave DS write->read ordering, then coalesced 256B-run stores
        asm volatile("s_waitcnt lgkmcnt(0)" ::: "memory");
        __builtin_amdgcn_sched_barrier(0);
        const size_t gbyte = (size_t)p * 256;
        #pragma unroll
        for (int i = 0; i < 8; ++i) {            // 2 tiles x 4 row-quads
            const int row = (i >> 2) * 16 + (i & 3) * 4 + rr;
            uint4 v = *(const uint4*)&tr[wv][row][c16 * 8];
            *(uint4*)(G + (size_t)(r0 + row) * ROWB + gbyte + c16 * 16) = v;
        }
        asm volatile("s_waitcnt lgkmcnt(0)" ::: "memory");  // reads done before next pass
        __builtin_amdgcn_sched_barrier(0);
    }
}

// ---------------------------------------------------------------------------
// Scan kernel: one wave per batch. Contiguous 11x1KB DMA per step from
// row-major bf16 G (5-deep buffers, counted vmcnt(44) steady, never 0
// mid-loop). Lane l = (k-quad q=l&15, h-range hr=l>>4); b64 bf16 reads +
// shift-extract; split accumulators; shfl_xor reduce; fp32 math.
// ---------------------------------------------------------------------------
__global__ __launch_bounds__(64, 1) void scan_kernel(
    const unsigned char* __restrict__ ws,
    const float* __restrict__ x_m,
    const float* __restrict__ Wfc, const float* __restrict__ bfc,
    float* __restrict__ out, int t0, int chunk, int first)
{
    const int b = blockIdx.x, l = threadIdx.x;
    const int q = l & 15, hr = l >> 4;
    const unsigned char* G = ws + OG;

    __shared__ __align__(16) unsigned char buf[5][ROWB];    // 56.3KB
    __shared__ __align__(16) float c_sh[64];
    __shared__ __align__(16) float xm_s[4096];              // chunk<=256

    float* cbase = out + B;   // c region: cbase[(b*T + t)*H + k]

    {   // stage x_m chunk
        const float4* src = (const float4*)(x_m + ((size_t)b * T + t0) * M);
        float4* dst = (float4*)xm_s;
        for (int i = l; i < chunk * 4; i += 64) dst[i] = src[i];
    }
    c_sh[l] = first ? 0.f : cbase[((size_t)b * T + (t0 - 1)) * H + l];
    const float4 wfc4 = *(const float4*)&Wfc[q * 4];
    const float bfc0 = bfc[0];
    asm volatile("s_waitcnt vmcnt(0) lgkmcnt(0)" ::: "memory");

#define DMA(tc_)                                                                \
    {                                                                           \
        const unsigned char* rp_ = G + (size_t)(b * chunk + (tc_)) * ROWB;      \
        unsigned char* lb_ = &buf[(tc_) % 5][0];                                \
        _Pragma("unroll")                                                       \
        for (int i_ = 0; i_ < 11; ++i_)                                         \
            __builtin_amdgcn_global_load_lds(                                   \
                (const __attribute__((address_space(1))) unsigned int*)         \
                    (rp_ + i_ * 1024 + l * 16),                                 \
                (__attribute__((address_space(3))) unsigned int*)               \
                    (lb_ + i_ * 1024), 16, 0, 0);                               \
    }

    DMA(0); DMA(1); DMA(2); DMA(3); DMA(4);

    for (int tc = 0; tc < chunk; ++tc) {
        // counted waits: N = 11 * (future DMA batches in flight); stores add
        // slack only (retire-order older), never a deficit.
        if      (tc + 5 <= chunk) asm volatile("s_waitcnt vmcnt(44)" ::: "memory");
        else if (tc + 4 == chunk) asm volatile("s_waitcnt vmcnt(33)" ::: "memory");
        else if (tc + 3 == chunk) asm volatile("s_waitcnt vmcnt(22)" ::: "memory");
        else if (tc + 2 == chunk) asm volatile("s_waitcnt vmcnt(11)" ::: "memory");
        else                      asm volatile("s_waitcnt vmcnt(0)"  ::: "memory");
        __builtin_amdgcn_sched_barrier(0);

        const ushort* bp = (const ushort*)&buf[tc % 5][0];

        float cc[16];
        #pragma unroll
        for (int i = 0; i < 16; ++i) cc[i] = c_sh[hr * 16 + i];
        float xm[4];
        #pragma unroll
        for (int j = 0; j < 4; ++j) xm[j] = xm_s[tc * 16 + hr * 4 + j];

        float a0 = 0.f, a1 = 0.f, a2 = 0.f, a3 = 0.f;
        #pragma unroll
        for (int j = 0; j < 4; ++j) {   // J: g = hr*4+j
            const uint2 u = *(const uint2*)(bp + (hr * 4 + j) * 64 + q * 4);
            a0 += xm[j] * blo(u.x); a1 += xm[j] * bhi(u.x);
            a2 += xm[j] * blo(u.y); a3 += xm[j] * bhi(u.y);
        }
        float e0 = 0.f, e1 = 0.f, e2 = 0.f, e3 = 0.f;   // split accumulators
        #pragma unroll
        for (int i = 0; i < 16; i += 2) {  // R: h = hr*16+i
            const uint2 u0 = *(const uint2*)(bp + 1024 + (hr * 16 + i) * 64 + q * 4);
            const uint2 u1 = *(const uint2*)(bp + 1024 + (hr * 16 + i + 1) * 64 + q * 4);
            a0 += cc[i] * blo(u0.x);     a1 += cc[i] * bhi(u0.x);
            a2 += cc[i] * blo(u0.y);     a3 += cc[i] * bhi(u0.y);
            e0 += cc[i + 1] * blo(u1.x); e1 += cc[i + 1] * bhi(u1.x);
            e2 += cc[i + 1] * blo(u1.y); e3 += cc[i + 1] * bhi(u1.y);
        }
        a0 += e0; a1 += e1; a2 += e2; a3 += e3;
        const uint2 uo = *(const uint2*)(bp + 5120 + q * 4);
        const float o0 = blo(uo.x), o1 = bhi(uo.x), o2 = blo(uo.y), o3 = bhi(uo.y);

        a0 += __shfl_xor(a0, 16); a1 += __shfl_xor(a1, 16);
        a2 += __shfl_xor(a2, 16); a3 += __shfl_xor(a3, 16);
        a0 += __shfl_xor(a0, 32); a1 += __shfl_xor(a1, 32);
        a2 += __shfl_xor(a2, 32); a3 += __shfl_xor(a3, 32);

        const float cn0 = (1.f - o0) * a0;
        const float cn1 = (1.f - o1) * a1;
        const float cn2 = (1.f - o2) * a2;
        const float cn3 = (1.f - o3) * a3;

        if (hr == 0) {
            *(float4*)&c_sh[q * 4] = make_float4(cn0, cn1, cn2, cn3);
            *(float4*)(cbase + ((size_t)b * T + t0 + tc) * H + q * 4) =
                make_float4(cn0, cn1, cn2, cn3);
        }
        if (t0 + tc == T - 1) {
            float v = o0 * a0 * wfc4.x + o1 * a1 * wfc4.y +
                      o2 * a2 * wfc4.z + o3 * a3 * wfc4.w;
            v += __shfl_xor(v, 1); v += __shfl_xor(v, 2);
            v += __shfl_xor(v, 4); v += __shfl_xor(v, 8);
            if (l == 0) out[b] = v + bfc0;
        }

        if (tc + 5 < chunk) {
            asm volatile("s_waitcnt lgkmcnt(0)" ::: "memory");  // buf reads done
            DMA(tc + 5);
        }
    }
#undef DMA
}

// ---------------------------------------------------------------------------
extern "C" void kernel_launch(void* const* d_in, const int* in_sizes, int n_in,
                              void* d_out, int out_size, void* d_ws, size_t ws_size,
                              hipStream_t stream) {
    const float* x_m = (const float*)d_in[0];
    const float* x_a = (const float*)d_in[1];
    const float* Wj  = (const float*)d_in[2];
    const float* bj  = (const float*)d_in[3];
    const float* Wr  = (const float*)d_in[4];
    const float* br  = (const float*)d_in[5];
    const float* Wo  = (const float*)d_in[6];
    const float* bo  = (const float*)d_in[7];
    const float* Wfc = (const float*)d_in[8];
    const float* bfc = (const float*)d_in[9];
    float* out = (float*)d_out;
    unsigned char* ws = (unsigned char*)d_ws;

    // largest time-chunk (multiple of 32) whose G fits in the workspace
    int chunk = 256;
    while (chunk > 32 && OG + (size_t)B * chunk * ROWB > ws_size) chunk >>= 1;

    {   // bf16 conversion + bias concat
        const int total = 5184 * 32 + B * T * A + 5184;
        prep_kernel<<<(total + 255) / 256, 256, 0, stream>>>(
            x_a, Wj, Wr, Wo, bj, br, bo, ws);
    }

    for (int t0 = 0; t0 < T; t0 += chunk) {
        gate_kernel<<<(B * chunk) / 32, 256, 0, stream>>>(ws, t0, chunk);
        scan_kernel<<<64, 64, 0, stream>>>(
            ws, x_m, Wfc, bfc, out, t0, chunk, t0 == 0 ? 1 : 0);
    }
}